// Round 1
// baseline (1504.727 us; speedup 1.0000x reference)
//
#include <hip/hip_runtime.h>
#include <hip/hip_bf16.h>
#include <stdint.h>

typedef __bf16 bf16_t;
typedef __bf16 bf16x8 __attribute__((ext_vector_type(8)));
typedef __bf16 bf16x4 __attribute__((ext_vector_type(4)));
typedef float  v4f    __attribute__((ext_vector_type(4)));

#define GLDS16(gp, lp)                                                         \
  __builtin_amdgcn_global_load_lds(                                            \
      (__attribute__((address_space(1))) void*)(gp),                           \
      (__attribute__((address_space(3))) void*)(lp), 16, 0, 0)

#define BATCH 2048
#define KEXP  64
#define NOUT  512
#define NTOT  1024   // W_con rows (512) ++ W_recon rows (512) per expert
#define R1    1024

// ---------------------------------------------------------------- cast u -> bf16
__global__ __launch_bounds__(256) void cast_u_k(const float* __restrict__ u,
                                                bf16_t* __restrict__ ub) {
  int idx = blockIdx.x * 256 + threadIdx.x;          // float4 index
  float4 v = ((const float4*)u)[idx];
  bf16x4 o;
  o.x = (bf16_t)v.x; o.y = (bf16_t)v.y; o.z = (bf16_t)v.z; o.w = (bf16_t)v.w;
  ((bf16x4*)ub)[idx] = o;
}

// ------------------------------------------- cast W_con|W_recon -> combined bf16
// wb layout: [k][n(0..1023)][i], n<512 from W_con, n>=512 from W_recon
__global__ __launch_bounds__(256) void cast_w_k(const float* __restrict__ wcon,
                                                const float* __restrict__ wrec,
                                                bf16_t* __restrict__ wb) {
  size_t idx = (size_t)blockIdx.x * 256 + threadIdx.x;  // float4 index
  size_t e = idx << 2;
  int k = (int)(e >> 20);
  int n = (int)((e >> 10) & 1023);
  int i = (int)(e & 1023);
  const float* src = (n < NOUT)
      ? (wcon + (((size_t)k * NOUT + n) << 10) + i)
      : (wrec + (((size_t)k * NOUT + (n - NOUT)) << 10) + i);
  float4 v = *(const float4*)src;
  bf16x4 o;
  o.x = (bf16_t)v.x; o.y = (bf16_t)v.y; o.z = (bf16_t)v.z; o.w = (bf16_t)v.w;
  ((bf16x4*)wb)[idx] = o;
}

// ---------------------------------------------------------------- psi (fp32)
// d2[b,k] = || sigma_inv[k]^T (mu_k - z_b) ||^2 ; psi = softmax_k(-d2)
// 256 threads: e = t&127 (output component), dh = t>>7 (d-half). 8 batches/block.
__global__ __launch_bounds__(256) void psi_k(const float* __restrict__ z,
                                             const float* __restrict__ mu,
                                             const float* __restrict__ sig,
                                             float* __restrict__ psi) {
  __shared__ float zs[8][128];
  __shared__ float dv[8][128];
  __shared__ float vh[2][8][128];
  __shared__ float red[2][8];
  __shared__ float d2s[8][64];
  const int t = threadIdx.x;
  const int e = t & 127, dh = t >> 7;
  const int b0 = blockIdx.x * 8;

  for (int b = dh; b < 8; b += 2) zs[b][e] = z[(size_t)(b0 + b) * 128 + e];
  __syncthreads();

  for (int k = 0; k < 64; ++k) {
    float muv = mu[k * 128 + e];
#pragma unroll
    for (int b = dh * 4; b < dh * 4 + 4; ++b) dv[b][e] = muv - zs[b][e];
    __syncthreads();

    float v[8];
#pragma unroll
    for (int b = 0; b < 8; ++b) v[b] = 0.f;
    const float* Sk = sig + ((size_t)k << 14) + (size_t)dh * 64 * 128 + e;
    for (int d4 = 0; d4 < 64; d4 += 4) {
      float s0 = Sk[(d4 + 0) * 128];
      float s1 = Sk[(d4 + 1) * 128];
      float s2 = Sk[(d4 + 2) * 128];
      float s3 = Sk[(d4 + 3) * 128];
      const int db = dh * 64 + d4;
#pragma unroll
      for (int b = 0; b < 8; ++b) {
        float4 dq = *(const float4*)&dv[b][db];   // LDS broadcast read
        v[b] += s0 * dq.x + s1 * dq.y + s2 * dq.z + s3 * dq.w;
      }
    }
#pragma unroll
    for (int b = 0; b < 8; ++b) vh[dh][b][e] = v[b];
    __syncthreads();

    if (t < 128) {  // waves 0,1 fully active -> wave-uniform branch
#pragma unroll
      for (int b = 0; b < 8; ++b) {
        float ve = vh[0][b][e] + vh[1][b][e];
        float x = ve * ve;
        x += __shfl_xor(x, 1);  x += __shfl_xor(x, 2);  x += __shfl_xor(x, 4);
        x += __shfl_xor(x, 8);  x += __shfl_xor(x, 16); x += __shfl_xor(x, 32);
        if ((t & 63) == 0) red[t >> 6][b] = x;
      }
    }
    __syncthreads();
    if (t < 8) d2s[t][k] = red[0][t] + red[1][t];
  }
  __syncthreads();

  if (t < 64) {  // wave 0: softmax over k per batch
    for (int b = 0; b < 8; ++b) {
      float x = fmaxf(d2s[b][t], 0.0f);  // MIN_CLAMP
      float m = x;
      m = fminf(m, __shfl_xor(m, 1));  m = fminf(m, __shfl_xor(m, 2));
      m = fminf(m, __shfl_xor(m, 4));  m = fminf(m, __shfl_xor(m, 8));
      m = fminf(m, __shfl_xor(m, 16)); m = fminf(m, __shfl_xor(m, 32));
      float ex = __expf(m - x);
      float s = ex;
      s += __shfl_xor(s, 1);  s += __shfl_xor(s, 2);  s += __shfl_xor(s, 4);
      s += __shfl_xor(s, 8);  s += __shfl_xor(s, 16); s += __shfl_xor(s, 32);
      psi[(size_t)(b0 + b) * 64 + t] = ex / s;
    }
  }
}

// ------------------------------------------------------- fused bf16 MFMA GEMM
// grid (16 m-tiles, 8 n-tiles, 8 expert-chunks), 256 thr, 128x128 tile, BK=64.
// Per expert: C = u . W[k]^T (K=1024), then oacc += |C| * w[b,k]; atomicAdd out.
__global__ __launch_bounds__(256, 2)
void fused_gemm(const bf16_t* __restrict__ ub,   // [2048][1024]
                const bf16_t* __restrict__ wb,   // [64][1024][1024]
                const float* __restrict__ psi,   // [2048][64]
                const float* __restrict__ member,// [2048][64]
                float* __restrict__ out) {       // y[2048*512] ++ x[2048*512]
  __shared__ bf16_t Alds[128 * 64];
  __shared__ bf16_t Blds[128 * 64];
  __shared__ float wlds[128];

  const int t = threadIdx.x, lane = t & 63, wv = t >> 6;
  const int bm0 = blockIdx.x * 128;
  const int n0  = blockIdx.y * 128;
  const int e0  = blockIdx.z * 8;
  const bool is_y = (n0 < NOUT);
  const float* wsel = is_y ? psi : member;
  const int wm = wv & 1, wn = wv >> 1;
  const int l15 = lane & 15, quad = lane >> 4;

  v4f acc[4][4], oacc[4][4];
#pragma unroll
  for (int mi = 0; mi < 4; ++mi)
#pragma unroll
    for (int ni = 0; ni < 4; ++ni)
#pragma unroll
      for (int r = 0; r < 4; ++r) { acc[mi][ni][r] = 0.f; oacc[mi][ni][r] = 0.f; }

  const int rA = wv * 8 + (lane >> 3);       // staging row within 32-row group
  const int c8 = (lane & 7) * 8;             // staging col (bf16 elements)
  const bf16_t* au  = ub + (size_t)(bm0 + rA) * R1 + c8;
  const bf16_t* bw0 = wb + (size_t)(n0 + rA) * R1 + c8;

  for (int ke = 0; ke < 8; ++ke) {
    const int ex = e0 + ke;
    const bf16_t* bw = bw0 + ((size_t)ex << 20);
    for (int kk = 0; kk < R1; kk += 64) {
      __syncthreads();  // LDS safe to overwrite
      if (kk == 0 && t < 128) wlds[t] = wsel[(size_t)(bm0 + t) * 64 + ex];
#pragma unroll
      for (int j = 0; j < 4; ++j) {
        GLDS16(au + (size_t)(j * 32) * R1 + kk, &Alds[(j * 32 + wv * 8) * 64]);
        GLDS16(bw + (size_t)(j * 32) * R1 + kk, &Blds[(j * 32 + wv * 8) * 64]);
      }
      __syncthreads();  // staging complete (vmcnt drained by barrier)

      const bf16_t* Ab = &Alds[(wm * 64 + l15) * 64 + quad * 8];
      const bf16_t* Bb = &Blds[(wn * 64 + l15) * 64 + quad * 8];
#pragma unroll
      for (int ks = 0; ks < 2; ++ks) {
        bf16x8 af[4], bfr[4];
#pragma unroll
        for (int i = 0; i < 4; ++i) {
          af[i]  = *(const bf16x8*)(Ab + i * 16 * 64 + ks * 32);
          bfr[i] = *(const bf16x8*)(Bb + i * 16 * 64 + ks * 32);
        }
#pragma unroll
        for (int mi = 0; mi < 4; ++mi)
#pragma unroll
          for (int ni = 0; ni < 4; ++ni)
            acc[mi][ni] = __builtin_amdgcn_mfma_f32_16x16x32_bf16(
                af[mi], bfr[ni], acc[mi][ni], 0, 0, 0);
      }
    }
    // per-expert epilogue: oacc += |acc| * w[b, ex]; reset acc
#pragma unroll
    for (int mi = 0; mi < 4; ++mi) {
      float wr[4];
#pragma unroll
      for (int r = 0; r < 4; ++r) wr[r] = wlds[wm * 64 + mi * 16 + quad * 4 + r];
#pragma unroll
      for (int ni = 0; ni < 4; ++ni)
#pragma unroll
        for (int r = 0; r < 4; ++r) {
          oacc[mi][ni][r] += fabsf(acc[mi][ni][r]) * wr[r];
          acc[mi][ni][r] = 0.f;
        }
    }
  }

  float* obase = is_y ? out : out + (size_t)BATCH * NOUT;
  const int oc = (is_y ? n0 : n0 - NOUT) + wn * 64 + l15;
#pragma unroll
  for (int mi = 0; mi < 4; ++mi)
#pragma unroll
    for (int ni = 0; ni < 4; ++ni)
#pragma unroll
      for (int r = 0; r < 4; ++r) {
        int brow = bm0 + wm * 64 + mi * 16 + quad * 4 + r;
        atomicAdd(&obase[(size_t)brow * NOUT + oc + ni * 16], oacc[mi][ni][r]);
      }
}

extern "C" void kernel_launch(void* const* d_in, const int* in_sizes, int n_in,
                              void* d_out, int out_size, void* d_ws, size_t ws_size,
                              hipStream_t stream) {
  const float* z    = (const float*)d_in[0];
  const float* u    = (const float*)d_in[1];
  const float* mem  = (const float*)d_in[2];
  const float* mu   = (const float*)d_in[3];
  const float* sig  = (const float*)d_in[4];
  const float* wcon = (const float*)d_in[5];
  const float* wrec = (const float*)d_in[6];
  float* out = (float*)d_out;

  char* ws = (char*)d_ws;
  bf16_t* ub  = (bf16_t*)ws;                              // 4 MiB
  bf16_t* wb  = (bf16_t*)(ws + ((size_t)4 << 20));        // 128 MiB
  float*  psw = (float*)(ws + ((size_t)132 << 20));       // 512 KiB

  hipMemsetAsync(d_out, 0, (size_t)out_size * sizeof(float), stream);
  cast_u_k<<<2048, 256, 0, stream>>>(u, ub);
  cast_w_k<<<65536, 256, 0, stream>>>(wcon, wrec, wb);
  psi_k<<<256, 256, 0, stream>>>(z, mu, sig, psw);
  fused_gemm<<<dim3(16, 8, 8), 256, 0, stream>>>(ub, wb, psw, mem, out);
}

// Round 2
// 863.123 us; speedup vs baseline: 1.7434x; 1.7434x over previous
//
#include <hip/hip_runtime.h>
#include <hip/hip_bf16.h>
#include <stdint.h>

typedef __bf16 bf16_t;
typedef __bf16 bf16x8 __attribute__((ext_vector_type(8)));
typedef __bf16 bf16x4 __attribute__((ext_vector_type(4)));
typedef float  v4f    __attribute__((ext_vector_type(4)));

#define GLDS16(gp, lp)                                                         \
  __builtin_amdgcn_global_load_lds(                                            \
      (__attribute__((address_space(1))) void*)(gp),                           \
      (__attribute__((address_space(3))) void*)(lp), 16, 0, 0)

#define BATCH 2048
#define KEXP  64
#define NOUT  512
#define R1    1024

// ---------------------------------------------------------------- cast u -> bf16
__global__ __launch_bounds__(256) void cast_u_k(const float* __restrict__ u,
                                                bf16_t* __restrict__ ub) {
  int idx = blockIdx.x * 256 + threadIdx.x;          // float4 index
  float4 v = ((const float4*)u)[idx];
  bf16x4 o;
  o.x = (bf16_t)v.x; o.y = (bf16_t)v.y; o.z = (bf16_t)v.z; o.w = (bf16_t)v.w;
  ((bf16x4*)ub)[idx] = o;
}

// ------------------------------------------- cast W_con|W_recon -> combined bf16
// wb layout: [k][n(0..1023)][i], n<512 from W_con, n>=512 from W_recon
__global__ __launch_bounds__(256) void cast_w_k(const float* __restrict__ wcon,
                                                const float* __restrict__ wrec,
                                                bf16_t* __restrict__ wb) {
  size_t idx = (size_t)blockIdx.x * 256 + threadIdx.x;  // float4 index
  size_t e = idx << 2;
  int k = (int)(e >> 20);
  int n = (int)((e >> 10) & 1023);
  int i = (int)(e & 1023);
  const float* src = (n < NOUT)
      ? (wcon + (((size_t)k * NOUT + n) << 10) + i)
      : (wrec + (((size_t)k * NOUT + (n - NOUT)) << 10) + i);
  float4 v = *(const float4*)src;
  bf16x4 o;
  o.x = (bf16_t)v.x; o.y = (bf16_t)v.y; o.z = (bf16_t)v.z; o.w = (bf16_t)v.w;
  ((bf16x4*)wb)[idx] = o;
}

// ------------------------------------------------------------- d2 (fp32, VALU)
// d2[b,k] = || sigma_inv[k]^T (mu_k - z_b) ||^2
// lane = batch row (dv in 128 registers); sigma columns via wave-uniform
// scalar loads (s_load_dwordx4), 4 e-columns per iter -> 1 s_load : 4 v_fma.
// grid (64 k, 16 b-tiles), 128 threads. No LDS, no barriers in hot path.
__global__ __launch_bounds__(128) void psi_d2_k(const float* __restrict__ z,
                                                const float* __restrict__ mu,
                                                const float* __restrict__ sig,
                                                float* __restrict__ d2g) {
  const int t = threadIdx.x;            // 0..127 -> batch lane
  const int k = blockIdx.x;             // expert
  const int b0 = blockIdx.y * 128;      // batch tile

  // dv[d] = mu[k][d] - z[b0+t][d], held entirely in VGPRs.
  float dv[128];
  const float* zrow = z + (size_t)(b0 + t) * 128;
  const float* muk = mu + k * 128;      // wave-uniform -> s_load
#pragma unroll
  for (int i = 0; i < 32; ++i) {
    float4 q = ((const float4*)zrow)[i];
    dv[4 * i + 0] = muk[4 * i + 0] - q.x;
    dv[4 * i + 1] = muk[4 * i + 1] - q.y;
    dv[4 * i + 2] = muk[4 * i + 2] - q.z;
    dv[4 * i + 3] = muk[4 * i + 3] - q.w;
  }

  const float* Sk = sig + ((size_t)k << 14);   // S[k][d][e]
  float d2 = 0.f;
  for (int e = 0; e < 128; e += 4) {           // 4 output components at a time
    float v0 = 0.f, v1 = 0.f, v2 = 0.f, v3 = 0.f;
#pragma unroll
    for (int d = 0; d < 128; ++d) {
      const float* srow = Sk + d * 128 + e;    // wave-uniform -> s_load_dwordx4
      v0 = fmaf(srow[0], dv[d], v0);
      v1 = fmaf(srow[1], dv[d], v1);
      v2 = fmaf(srow[2], dv[d], v2);
      v3 = fmaf(srow[3], dv[d], v3);
    }
    d2 = fmaf(v0, v0, d2);
    d2 = fmaf(v1, v1, d2);
    d2 = fmaf(v2, v2, d2);
    d2 = fmaf(v3, v3, d2);
  }
  d2g[(size_t)(b0 + t) * 64 + k] = d2;
}

// ----------------------------------------------------------- softmax over k
// one wave per batch row; lane = k (64 experts = 64 lanes).
__global__ __launch_bounds__(256) void psi_sm_k(const float* __restrict__ d2g,
                                                float* __restrict__ psi) {
  const int b = blockIdx.x * 4 + (threadIdx.x >> 6);
  const int lane = threadIdx.x & 63;
  float x = fmaxf(d2g[(size_t)b * 64 + lane], 0.0f);  // MIN_CLAMP
  float m = x;
  m = fminf(m, __shfl_xor(m, 1));  m = fminf(m, __shfl_xor(m, 2));
  m = fminf(m, __shfl_xor(m, 4));  m = fminf(m, __shfl_xor(m, 8));
  m = fminf(m, __shfl_xor(m, 16)); m = fminf(m, __shfl_xor(m, 32));
  float ex = __expf(m - x);
  float s = ex;
  s += __shfl_xor(s, 1);  s += __shfl_xor(s, 2);  s += __shfl_xor(s, 4);
  s += __shfl_xor(s, 8);  s += __shfl_xor(s, 16); s += __shfl_xor(s, 32);
  psi[(size_t)b * 64 + lane] = ex / s;
}

// ------------------------------------------------------- fused bf16 MFMA GEMM
// grid (16 m-tiles, 8 n-tiles, 8 expert-chunks), 256 thr, 128x128 tile, BK=64.
// Per expert: C = u . W[k]^T (K=1024), then oacc += |C| * w[b,k]; atomicAdd out.
__global__ __launch_bounds__(256, 2)
void fused_gemm(const bf16_t* __restrict__ ub,   // [2048][1024]
                const bf16_t* __restrict__ wb,   // [64][1024][1024]
                const float* __restrict__ psi,   // [2048][64]
                const float* __restrict__ member,// [2048][64]
                float* __restrict__ out) {       // y[2048*512] ++ x[2048*512]
  __shared__ bf16_t Alds[128 * 64];
  __shared__ bf16_t Blds[128 * 64];
  __shared__ float wlds[128];

  const int t = threadIdx.x, lane = t & 63, wv = t >> 6;
  const int bm0 = blockIdx.x * 128;
  const int n0  = blockIdx.y * 128;
  const int e0  = blockIdx.z * 8;
  const bool is_y = (n0 < NOUT);
  const float* wsel = is_y ? psi : member;
  const int wm = wv & 1, wn = wv >> 1;
  const int l15 = lane & 15, quad = lane >> 4;

  v4f acc[4][4], oacc[4][4];
#pragma unroll
  for (int mi = 0; mi < 4; ++mi)
#pragma unroll
    for (int ni = 0; ni < 4; ++ni)
#pragma unroll
      for (int r = 0; r < 4; ++r) { acc[mi][ni][r] = 0.f; oacc[mi][ni][r] = 0.f; }

  const int rA = wv * 8 + (lane >> 3);       // staging row within 32-row group
  const int c8 = (lane & 7) * 8;             // staging col (bf16 elements)
  const bf16_t* au  = ub + (size_t)(bm0 + rA) * R1 + c8;
  const bf16_t* bw0 = wb + (size_t)(n0 + rA) * R1 + c8;

  for (int ke = 0; ke < 8; ++ke) {
    const int ex = e0 + ke;
    const bf16_t* bw = bw0 + ((size_t)ex << 20);
    for (int kk = 0; kk < R1; kk += 64) {
      __syncthreads();  // LDS safe to overwrite
      if (kk == 0 && t < 128) wlds[t] = wsel[(size_t)(bm0 + t) * 64 + ex];
#pragma unroll
      for (int j = 0; j < 4; ++j) {
        GLDS16(au + (size_t)(j * 32) * R1 + kk, &Alds[(j * 32 + wv * 8) * 64]);
        GLDS16(bw + (size_t)(j * 32) * R1 + kk, &Blds[(j * 32 + wv * 8) * 64]);
      }
      __syncthreads();  // staging complete (vmcnt drained by barrier)

      const bf16_t* Ab = &Alds[(wm * 64 + l15) * 64 + quad * 8];
      const bf16_t* Bb = &Blds[(wn * 64 + l15) * 64 + quad * 8];
#pragma unroll
      for (int ks = 0; ks < 2; ++ks) {
        bf16x8 af[4], bfr[4];
#pragma unroll
        for (int i = 0; i < 4; ++i) {
          af[i]  = *(const bf16x8*)(Ab + i * 16 * 64 + ks * 32);
          bfr[i] = *(const bf16x8*)(Bb + i * 16 * 64 + ks * 32);
        }
#pragma unroll
        for (int mi = 0; mi < 4; ++mi)
#pragma unroll
          for (int ni = 0; ni < 4; ++ni)
            acc[mi][ni] = __builtin_amdgcn_mfma_f32_16x16x32_bf16(
                af[mi], bfr[ni], acc[mi][ni], 0, 0, 0);
      }
    }
    // per-expert epilogue: oacc += |acc| * w[b, ex]; reset acc
#pragma unroll
    for (int mi = 0; mi < 4; ++mi) {
      float wr[4];
#pragma unroll
      for (int r = 0; r < 4; ++r) wr[r] = wlds[wm * 64 + mi * 16 + quad * 4 + r];
#pragma unroll
      for (int ni = 0; ni < 4; ++ni)
#pragma unroll
        for (int r = 0; r < 4; ++r) {
          oacc[mi][ni][r] += fabsf(acc[mi][ni][r]) * wr[r];
          acc[mi][ni][r] = 0.f;
        }
    }
  }

  float* obase = is_y ? out : out + (size_t)BATCH * NOUT;
  const int oc = (is_y ? n0 : n0 - NOUT) + wn * 64 + l15;
#pragma unroll
  for (int mi = 0; mi < 4; ++mi)
#pragma unroll
    for (int ni = 0; ni < 4; ++ni)
#pragma unroll
      for (int r = 0; r < 4; ++r) {
        int brow = bm0 + wm * 64 + mi * 16 + quad * 4 + r;
        atomicAdd(&obase[(size_t)brow * NOUT + oc + ni * 16], oacc[mi][ni][r]);
      }
}

extern "C" void kernel_launch(void* const* d_in, const int* in_sizes, int n_in,
                              void* d_out, int out_size, void* d_ws, size_t ws_size,
                              hipStream_t stream) {
  const float* z    = (const float*)d_in[0];
  const float* u    = (const float*)d_in[1];
  const float* mem  = (const float*)d_in[2];
  const float* mu   = (const float*)d_in[3];
  const float* sig  = (const float*)d_in[4];
  const float* wcon = (const float*)d_in[5];
  const float* wrec = (const float*)d_in[6];
  float* out = (float*)d_out;

  char* ws = (char*)d_ws;
  bf16_t* ub  = (bf16_t*)ws;                              // 4 MiB
  bf16_t* wb  = (bf16_t*)(ws + ((size_t)4 << 20));        // 128 MiB
  float*  psw = (float*)(ws + ((size_t)132 << 20));       // 512 KiB
  float*  d2g = (float*)(ws + ((size_t)132 << 20) + ((size_t)512 << 10));

  hipMemsetAsync(d_out, 0, (size_t)out_size * sizeof(float), stream);
  cast_u_k<<<2048, 256, 0, stream>>>(u, ub);
  cast_w_k<<<65536, 256, 0, stream>>>(wcon, wrec, wb);
  psi_d2_k<<<dim3(64, 16), 128, 0, stream>>>(z, mu, sig, d2g);
  psi_sm_k<<<512, 256, 0, stream>>>(d2g, psw);
  fused_gemm<<<dim3(16, 8, 8), 256, 0, stream>>>(ub, wb, psw, mem, out);
}

// Round 3
// 695.764 us; speedup vs baseline: 2.1627x; 1.2405x over previous
//
#include <hip/hip_runtime.h>
#include <hip/hip_bf16.h>
#include <stdint.h>

typedef __bf16 bf16_t;
typedef __bf16 bf16x8 __attribute__((ext_vector_type(8)));
typedef __bf16 bf16x4 __attribute__((ext_vector_type(4)));
typedef float  v4f    __attribute__((ext_vector_type(4)));

#define GLDS16(gp, lp)                                                         \
  __builtin_amdgcn_global_load_lds(                                            \
      (__attribute__((address_space(1))) void*)(gp),                           \
      (__attribute__((address_space(3))) void*)(lp), 16, 0, 0)

#define BATCH 2048
#define KEXP  64
#define NOUT  512
#define R1    1024

// ---------------------------------------------------------------- cast u -> bf16
__global__ __launch_bounds__(256) void cast_u_k(const float* __restrict__ u,
                                                bf16_t* __restrict__ ub) {
  int idx = blockIdx.x * 256 + threadIdx.x;          // float4 index
  float4 v = ((const float4*)u)[idx];
  bf16x4 o;
  o.x = (bf16_t)v.x; o.y = (bf16_t)v.y; o.z = (bf16_t)v.z; o.w = (bf16_t)v.w;
  ((bf16x4*)ub)[idx] = o;
}

// ------------------------------------------- cast W_con|W_recon -> combined bf16
// wb layout: [k][n(0..1023)][i], n<512 from W_con, n>=512 from W_recon
__global__ __launch_bounds__(256) void cast_w_k(const float* __restrict__ wcon,
                                                const float* __restrict__ wrec,
                                                bf16_t* __restrict__ wb) {
  size_t idx = (size_t)blockIdx.x * 256 + threadIdx.x;  // float4 index
  size_t e = idx << 2;
  int k = (int)(e >> 20);
  int n = (int)((e >> 10) & 1023);
  int i = (int)(e & 1023);
  const float* src = (n < NOUT)
      ? (wcon + (((size_t)k * NOUT + n) << 10) + i)
      : (wrec + (((size_t)k * NOUT + (n - NOUT)) << 10) + i);
  float4 v = *(const float4*)src;
  bf16x4 o;
  o.x = (bf16_t)v.x; o.y = (bf16_t)v.y; o.z = (bf16_t)v.z; o.w = (bf16_t)v.w;
  ((bf16x4*)wb)[idx] = o;
}

// ------------------------------------------------------------- d2 (fp32 GEMM)
// d2[b,k] = || S_k^T (mu_k - z_b) ||^2.  Block = (k, 64-batch tile).
// dv staged in LDS (64 x 132 padded); S_k streamed via coalesced vector loads
// (L2-hot: reused by all 32 b-tiles). Thread tile 4b x 8e -> 32 FMA per d.
// Epilogue: in-register square + 16-lane shuffle reduce over e-threads.
__global__ __launch_bounds__(256) void psi_d2_k(const float* __restrict__ z,
                                                const float* __restrict__ mu,
                                                const float* __restrict__ sig,
                                                float* __restrict__ d2g) {
  __shared__ float dv[64][132];   // +4 pad: 16B-aligned rows, bank-shifted
  const int t = threadIdx.x;
  const int k = blockIdx.x;
  const int b0 = blockIdx.y * 64;

  const float* muk = mu + k * 128;
#pragma unroll
  for (int i = 0; i < 8; ++i) {
    int f4 = i * 256 + t;                 // float4 index within 64x128 tile
    int row = f4 >> 5, c4 = f4 & 31;
    float4 zq = ((const float4*)(z + (size_t)(b0 + row) * 128))[c4];
    float4 mq = ((const float4*)muk)[c4];
    float4 dq;
    dq.x = mq.x - zq.x; dq.y = mq.y - zq.y;
    dq.z = mq.z - zq.z; dq.w = mq.w - zq.w;
    *(float4*)&dv[row][c4 * 4] = dq;
  }
  __syncthreads();

  const int et = t & 15, bt = t >> 4;     // e-thread, b-thread
  const float* Sb = sig + ((size_t)k << 14) + et * 8;
  float acc[4][8];
#pragma unroll
  for (int j = 0; j < 4; ++j)
#pragma unroll
    for (int i = 0; i < 8; ++i) acc[j][i] = 0.f;

#pragma unroll 4
  for (int d4 = 0; d4 < 32; ++d4) {
    float4 a[4];
#pragma unroll
    for (int j = 0; j < 4; ++j) a[j] = *(const float4*)&dv[bt * 4 + j][d4 * 4];
#pragma unroll
    for (int dd = 0; dd < 4; ++dd) {
      const float* srow = Sb + (size_t)(d4 * 4 + dd) * 128;
      float4 s0 = *(const float4*)srow;
      float4 s1 = *(const float4*)(srow + 4);
      float av[4] = {a[0][dd], a[1][dd], a[2][dd], a[3][dd]};
#pragma unroll
      for (int j = 0; j < 4; ++j) {
        acc[j][0] = fmaf(s0.x, av[j], acc[j][0]);
        acc[j][1] = fmaf(s0.y, av[j], acc[j][1]);
        acc[j][2] = fmaf(s0.z, av[j], acc[j][2]);
        acc[j][3] = fmaf(s0.w, av[j], acc[j][3]);
        acc[j][4] = fmaf(s1.x, av[j], acc[j][4]);
        acc[j][5] = fmaf(s1.y, av[j], acc[j][5]);
        acc[j][6] = fmaf(s1.z, av[j], acc[j][6]);
        acc[j][7] = fmaf(s1.w, av[j], acc[j][7]);
      }
    }
  }

  // partial d2 per thread: sum of squares over its 8 e-components
  float v2[4];
#pragma unroll
  for (int j = 0; j < 4; ++j) {
    float s = 0.f;
#pragma unroll
    for (int i = 0; i < 8; ++i) s = fmaf(acc[j][i], acc[j][i], s);
    v2[j] = s;
  }
  // reduce over the 16 e-threads (lanes et = lane&15)
#pragma unroll
  for (int j = 0; j < 4; ++j) {
    v2[j] += __shfl_xor(v2[j], 1);
    v2[j] += __shfl_xor(v2[j], 2);
    v2[j] += __shfl_xor(v2[j], 4);
    v2[j] += __shfl_xor(v2[j], 8);
  }
  if (et == 0) {
#pragma unroll
    for (int j = 0; j < 4; ++j)
      d2g[(size_t)(b0 + bt * 4 + j) * 64 + k] = v2[j];
  }
}

// ----------------------------------------------------------- softmax over k
// one wave per batch row; lane = k (64 experts = 64 lanes).
__global__ __launch_bounds__(256) void psi_sm_k(const float* __restrict__ d2g,
                                                float* __restrict__ psi) {
  const int b = blockIdx.x * 4 + (threadIdx.x >> 6);
  const int lane = threadIdx.x & 63;
  float x = fmaxf(d2g[(size_t)b * 64 + lane], 0.0f);  // MIN_CLAMP
  float m = x;
  m = fminf(m, __shfl_xor(m, 1));  m = fminf(m, __shfl_xor(m, 2));
  m = fminf(m, __shfl_xor(m, 4));  m = fminf(m, __shfl_xor(m, 8));
  m = fminf(m, __shfl_xor(m, 16)); m = fminf(m, __shfl_xor(m, 32));
  float ex = __expf(m - x);
  float s = ex;
  s += __shfl_xor(s, 1);  s += __shfl_xor(s, 2);  s += __shfl_xor(s, 4);
  s += __shfl_xor(s, 8);  s += __shfl_xor(s, 16); s += __shfl_xor(s, 32);
  psi[(size_t)b * 64 + lane] = ex / s;
}

// ------------------------------------------------------- fused bf16 MFMA GEMM
// grid (16 m-tiles, 8 n-tiles, 8 expert-chunks), 256 thr, 128x128 tile, BK=64.
// Per expert: C = u . W[k]^T (K=1024), then oacc += |C| * w[b,k]; atomicAdd out.
// LDS XOR swizzle: physical 16B chunk = logical chunk ^ (row & 7). Staging
// realizes it via the SOURCE address (global_load_lds dest is lane-ordered;
// row&7 == lane>>3 for every staged row). Kills the 16-way read conflicts.
__global__ __launch_bounds__(256, 2)
void fused_gemm(const bf16_t* __restrict__ ub,   // [2048][1024]
                const bf16_t* __restrict__ wb,   // [64][1024][1024]
                const float* __restrict__ psi,   // [2048][64]
                const float* __restrict__ member,// [2048][64]
                float* __restrict__ out) {       // y[2048*512] ++ x[2048*512]
  __shared__ bf16_t Alds[128 * 64];
  __shared__ bf16_t Blds[128 * 64];
  __shared__ float wlds[128];

  const int t = threadIdx.x, lane = t & 63, wv = t >> 6;
  const int bm0 = blockIdx.x * 128;
  const int n0  = blockIdx.y * 128;
  const int e0  = blockIdx.z * 8;
  const bool is_y = (n0 < NOUT);
  const float* wsel = is_y ? psi : member;
  const int wm = wv & 1, wn = wv >> 1;
  const int l15 = lane & 15, quad = lane >> 4;

  v4f acc[4][4], oacc[4][4];
#pragma unroll
  for (int mi = 0; mi < 4; ++mi)
#pragma unroll
    for (int ni = 0; ni < 4; ++ni)
#pragma unroll
      for (int r = 0; r < 4; ++r) { acc[mi][ni][r] = 0.f; oacc[mi][ni][r] = 0.f; }

  const int rA = wv * 8 + (lane >> 3);             // staging row in 32-row group
  const int c8 = (((lane & 7) ^ (lane >> 3)) * 8); // swizzled source column
  const bf16_t* au  = ub + (size_t)(bm0 + rA) * R1 + c8;
  const bf16_t* bw0 = wb + (size_t)(n0 + rA) * R1 + c8;

  const int fsw = l15 & 7;                         // fragment-read swizzle key

  for (int ke = 0; ke < 8; ++ke) {
    const int ex = e0 + ke;
    const bf16_t* bw = bw0 + ((size_t)ex << 20);
    for (int kk = 0; kk < R1; kk += 64) {
      __syncthreads();  // LDS safe to overwrite
      if (kk == 0 && t < 128) wlds[t] = wsel[(size_t)(bm0 + t) * 64 + ex];
#pragma unroll
      for (int j = 0; j < 4; ++j) {
        GLDS16(au + (size_t)(j * 32) * R1 + kk, &Alds[(j * 32 + wv * 8) * 64]);
        GLDS16(bw + (size_t)(j * 32) * R1 + kk, &Blds[(j * 32 + wv * 8) * 64]);
      }
      __syncthreads();  // staging complete (vmcnt drained by barrier)

      const bf16_t* Ab = &Alds[(wm * 64 + l15) * 64];
      const bf16_t* Bb = &Blds[(wn * 64 + l15) * 64];
#pragma unroll
      for (int ks = 0; ks < 2; ++ks) {
        const int co = ((ks * 4 + quad) ^ fsw) * 8;  // swizzled chunk offset
        bf16x8 af[4], bfr[4];
#pragma unroll
        for (int i = 0; i < 4; ++i) {
          af[i]  = *(const bf16x8*)(Ab + i * 16 * 64 + co);
          bfr[i] = *(const bf16x8*)(Bb + i * 16 * 64 + co);
        }
#pragma unroll
        for (int mi = 0; mi < 4; ++mi)
#pragma unroll
          for (int ni = 0; ni < 4; ++ni)
            acc[mi][ni] = __builtin_amdgcn_mfma_f32_16x16x32_bf16(
                af[mi], bfr[ni], acc[mi][ni], 0, 0, 0);
      }
    }
    // per-expert epilogue: oacc += |acc| * w[b, ex]; reset acc
#pragma unroll
    for (int mi = 0; mi < 4; ++mi) {
      float wr[4];
#pragma unroll
      for (int r = 0; r < 4; ++r) wr[r] = wlds[wm * 64 + mi * 16 + quad * 4 + r];
#pragma unroll
      for (int ni = 0; ni < 4; ++ni)
#pragma unroll
        for (int r = 0; r < 4; ++r) {
          oacc[mi][ni][r] += fabsf(acc[mi][ni][r]) * wr[r];
          acc[mi][ni][r] = 0.f;
        }
    }
  }

  float* obase = is_y ? out : out + (size_t)BATCH * NOUT;
  const int oc = (is_y ? n0 : n0 - NOUT) + wn * 64 + l15;
#pragma unroll
  for (int mi = 0; mi < 4; ++mi)
#pragma unroll
    for (int ni = 0; ni < 4; ++ni)
#pragma unroll
      for (int r = 0; r < 4; ++r) {
        int brow = bm0 + wm * 64 + mi * 16 + quad * 4 + r;
        atomicAdd(&obase[(size_t)brow * NOUT + oc + ni * 16], oacc[mi][ni][r]);
      }
}

extern "C" void kernel_launch(void* const* d_in, const int* in_sizes, int n_in,
                              void* d_out, int out_size, void* d_ws, size_t ws_size,
                              hipStream_t stream) {
  const float* z    = (const float*)d_in[0];
  const float* u    = (const float*)d_in[1];
  const float* mem  = (const float*)d_in[2];
  const float* mu   = (const float*)d_in[3];
  const float* sig  = (const float*)d_in[4];
  const float* wcon = (const float*)d_in[5];
  const float* wrec = (const float*)d_in[6];
  float* out = (float*)d_out;

  char* ws = (char*)d_ws;
  bf16_t* ub  = (bf16_t*)ws;                              // 4 MiB
  bf16_t* wb  = (bf16_t*)(ws + ((size_t)4 << 20));        // 128 MiB
  float*  psw = (float*)(ws + ((size_t)132 << 20));       // 512 KiB
  float*  d2g = (float*)(ws + ((size_t)132 << 20) + ((size_t)512 << 10));

  hipMemsetAsync(d_out, 0, (size_t)out_size * sizeof(float), stream);
  cast_u_k<<<2048, 256, 0, stream>>>(u, ub);
  cast_w_k<<<65536, 256, 0, stream>>>(wcon, wrec, wb);
  psi_d2_k<<<dim3(64, 32), 256, 0, stream>>>(z, mu, sig, d2g);
  psi_sm_k<<<512, 256, 0, stream>>>(d2g, psw);
  fused_gemm<<<dim3(16, 8, 8), 256, 0, stream>>>(ub, wb, psw, mem, out);
}

// Round 4
// 676.966 us; speedup vs baseline: 2.2228x; 1.0278x over previous
//
#include <hip/hip_runtime.h>
#include <hip/hip_bf16.h>
#include <stdint.h>

typedef __bf16 bf16_t;
typedef __bf16 bf16x8 __attribute__((ext_vector_type(8)));
typedef __bf16 bf16x4 __attribute__((ext_vector_type(4)));
typedef float  v4f    __attribute__((ext_vector_type(4)));
typedef float  f32x4  __attribute__((ext_vector_type(4)));

#define GLDS16(gp, lp)                                                         \
  __builtin_amdgcn_global_load_lds(                                            \
      (__attribute__((address_space(1))) void*)(gp),                           \
      (__attribute__((address_space(3))) void*)(lp), 16, 0, 0)

#define BATCH 2048
#define KEXP  64
#define NOUT  512
#define R1    1024

// ---------------------------------------------------------------- cast u -> bf16
__global__ __launch_bounds__(256) void cast_u_k(const float* __restrict__ u,
                                                bf16_t* __restrict__ ub) {
  int idx = blockIdx.x * 256 + threadIdx.x;          // float4 index
  float4 v = ((const float4*)u)[idx];
  bf16x4 o;
  o.x = (bf16_t)v.x; o.y = (bf16_t)v.y; o.z = (bf16_t)v.z; o.w = (bf16_t)v.w;
  ((bf16x4*)ub)[idx] = o;
}

// ------------------------------------------- cast W_con|W_recon -> combined bf16
// wb layout: [k][n(0..1023)][i], n<512 from W_con, n>=512 from W_recon.
// Grid-stride, 8 float4/thread. Nontemporal loads: wcon/wrec are read exactly
// once — keep them from evicting wb (128 MiB) out of the 256 MiB L3, so
// fused_gemm's 16x re-reads of wb hit L3 instead of HBM.
__global__ __launch_bounds__(256) void cast_w_k(const float* __restrict__ wcon,
                                                const float* __restrict__ wrec,
                                                bf16_t* __restrict__ wb) {
  const size_t tid = (size_t)blockIdx.x * 256 + threadIdx.x;
#pragma unroll
  for (int it = 0; it < 8; ++it) {
    size_t idx = tid + (size_t)it * (8192u * 256u);   // float4 index
    size_t e = idx << 2;
    int k = (int)(e >> 20);
    int n = (int)((e >> 10) & 1023);
    int i = (int)(e & 1023);
    const float* src = (n < NOUT)
        ? (wcon + (((size_t)k * NOUT + n) << 10) + i)
        : (wrec + (((size_t)k * NOUT + (n - NOUT)) << 10) + i);
    f32x4 v = __builtin_nontemporal_load((const f32x4*)src);
    bf16x4 o;
    o.x = (bf16_t)v.x; o.y = (bf16_t)v.y; o.z = (bf16_t)v.z; o.w = (bf16_t)v.w;
    ((bf16x4*)wb)[idx] = o;
  }
}

// ------------------------------------------------------------- d2 (fp32 GEMM)
// d2[b,k] = || S_k^T (mu_k - z_b) ||^2.  Block = (k, 64-batch tile).
// dv staged in LDS (64 x 132 padded); S_k staged through LDS in 16-row (8 KB)
// chunks with coalesced NON-redundant loads (v3: kills the 4x-lane-redundant
// per-thread VMEM stream that saturated L1 return BW). Thread tile 4b x 8e.
__global__ __launch_bounds__(256) void psi_d2_k(const float* __restrict__ z,
                                                const float* __restrict__ mu,
                                                const float* __restrict__ sig,
                                                float* __restrict__ d2g) {
  __shared__ float dv[64][132];   // +4 pad
  __shared__ float Ss[16][128];   // one 16-row chunk of S_k
  const int t = threadIdx.x;
  const int k = blockIdx.x;
  const int b0 = blockIdx.y * 64;

  const float* muk = mu + k * 128;
#pragma unroll
  for (int i = 0; i < 8; ++i) {
    int f4 = i * 256 + t;                 // float4 index within 64x128 tile
    int row = f4 >> 5, c4 = f4 & 31;
    float4 zq = ((const float4*)(z + (size_t)(b0 + row) * 128))[c4];
    float4 mq = ((const float4*)muk)[c4];
    float4 dq;
    dq.x = mq.x - zq.x; dq.y = mq.y - zq.y;
    dq.z = mq.z - zq.z; dq.w = mq.w - zq.w;
    *(float4*)&dv[row][c4 * 4] = dq;
  }

  const int et = t & 15, bt = t >> 4;     // e-thread, b-thread
  const float* Sk = sig + ((size_t)k << 14);
  float acc[4][8];
#pragma unroll
  for (int j = 0; j < 4; ++j)
#pragma unroll
    for (int i = 0; i < 8; ++i) acc[j][i] = 0.f;

  for (int dblk = 0; dblk < 8; ++dblk) {
    __syncthreads();                      // Ss safe to overwrite (also covers dv)
#pragma unroll
    for (int i = 0; i < 2; ++i) {
      int f4 = i * 256 + t;               // 0..511 within 16x128 chunk
      int row = f4 >> 5, c4 = f4 & 31;
      *(float4*)&Ss[row][c4 * 4] =
          ((const float4*)(Sk + (size_t)(dblk * 16 + row) * 128))[c4];
    }
    __syncthreads();

#pragma unroll
    for (int d4 = 0; d4 < 4; ++d4) {
      float4 a[4];
#pragma unroll
      for (int j = 0; j < 4; ++j)
        a[j] = *(const float4*)&dv[bt * 4 + j][dblk * 16 + d4 * 4];
#pragma unroll
      for (int dd = 0; dd < 4; ++dd) {
        float4 s0 = *(const float4*)&Ss[d4 * 4 + dd][et * 8];
        float4 s1 = *(const float4*)&Ss[d4 * 4 + dd][et * 8 + 4];
        float av[4] = {a[0][dd], a[1][dd], a[2][dd], a[3][dd]};
#pragma unroll
        for (int j = 0; j < 4; ++j) {
          acc[j][0] = fmaf(s0.x, av[j], acc[j][0]);
          acc[j][1] = fmaf(s0.y, av[j], acc[j][1]);
          acc[j][2] = fmaf(s0.z, av[j], acc[j][2]);
          acc[j][3] = fmaf(s0.w, av[j], acc[j][3]);
          acc[j][4] = fmaf(s1.x, av[j], acc[j][4]);
          acc[j][5] = fmaf(s1.y, av[j], acc[j][5]);
          acc[j][6] = fmaf(s1.z, av[j], acc[j][6]);
          acc[j][7] = fmaf(s1.w, av[j], acc[j][7]);
        }
      }
    }
  }

  // partial d2 per thread: sum of squares over its 8 e-components
  float v2[4];
#pragma unroll
  for (int j = 0; j < 4; ++j) {
    float s = 0.f;
#pragma unroll
    for (int i = 0; i < 8; ++i) s = fmaf(acc[j][i], acc[j][i], s);
    v2[j] = s;
  }
  // reduce over the 16 e-threads (lanes et = lane&15)
#pragma unroll
  for (int j = 0; j < 4; ++j) {
    v2[j] += __shfl_xor(v2[j], 1);
    v2[j] += __shfl_xor(v2[j], 2);
    v2[j] += __shfl_xor(v2[j], 4);
    v2[j] += __shfl_xor(v2[j], 8);
  }
  if (et == 0) {
#pragma unroll
    for (int j = 0; j < 4; ++j)
      d2g[(size_t)(b0 + bt * 4 + j) * 64 + k] = v2[j];
  }
}

// ----------------------------------------------------------- softmax over k
// one wave per batch row; lane = k (64 experts = 64 lanes).
__global__ __launch_bounds__(256) void psi_sm_k(const float* __restrict__ d2g,
                                                float* __restrict__ psi) {
  const int b = blockIdx.x * 4 + (threadIdx.x >> 6);
  const int lane = threadIdx.x & 63;
  float x = fmaxf(d2g[(size_t)b * 64 + lane], 0.0f);  // MIN_CLAMP
  float m = x;
  m = fminf(m, __shfl_xor(m, 1));  m = fminf(m, __shfl_xor(m, 2));
  m = fminf(m, __shfl_xor(m, 4));  m = fminf(m, __shfl_xor(m, 8));
  m = fminf(m, __shfl_xor(m, 16)); m = fminf(m, __shfl_xor(m, 32));
  float ex = __expf(m - x);
  float s = ex;
  s += __shfl_xor(s, 1);  s += __shfl_xor(s, 2);  s += __shfl_xor(s, 4);
  s += __shfl_xor(s, 8);  s += __shfl_xor(s, 16); s += __shfl_xor(s, 32);
  psi[(size_t)b * 64 + lane] = ex / s;
}

// ------------------------------------------------------- fused bf16 MFMA GEMM
// grid (16 m-tiles, 8 n-tiles, 8 expert-chunks), 256 thr, 128x128 tile, BK=64.
// Per expert: C = u . W[k]^T (K=1024), then oacc += |C| * w[b,k]; atomicAdd out.
// LDS XOR swizzle: physical 16B chunk = logical chunk ^ (row & 7), realized via
// the staging SOURCE address (row&7 == lane>>3). Zero bank conflicts (R3).
__global__ __launch_bounds__(256, 2)
void fused_gemm(const bf16_t* __restrict__ ub,   // [2048][1024]
                const bf16_t* __restrict__ wb,   // [64][1024][1024]
                const float* __restrict__ psi,   // [2048][64]
                const float* __restrict__ member,// [2048][64]
                float* __restrict__ out) {       // y[2048*512] ++ x[2048*512]
  __shared__ bf16_t Alds[128 * 64];
  __shared__ bf16_t Blds[128 * 64];
  __shared__ float wlds[128];

  const int t = threadIdx.x, lane = t & 63, wv = t >> 6;
  const int bm0 = blockIdx.x * 128;
  const int n0  = blockIdx.y * 128;
  const int e0  = blockIdx.z * 8;
  const bool is_y = (n0 < NOUT);
  const float* wsel = is_y ? psi : member;
  const int wm = wv & 1, wn = wv >> 1;
  const int l15 = lane & 15, quad = lane >> 4;

  v4f acc[4][4], oacc[4][4];
#pragma unroll
  for (int mi = 0; mi < 4; ++mi)
#pragma unroll
    for (int ni = 0; ni < 4; ++ni)
#pragma unroll
      for (int r = 0; r < 4; ++r) { acc[mi][ni][r] = 0.f; oacc[mi][ni][r] = 0.f; }

  const int rA = wv * 8 + (lane >> 3);             // staging row in 32-row group
  const int c8 = (((lane & 7) ^ (lane >> 3)) * 8); // swizzled source column
  const bf16_t* au  = ub + (size_t)(bm0 + rA) * R1 + c8;
  const bf16_t* bw0 = wb + (size_t)(n0 + rA) * R1 + c8;

  const int fsw = l15 & 7;                         // fragment-read swizzle key

  for (int ke = 0; ke < 8; ++ke) {
    const int ex = e0 + ke;
    const bf16_t* bw = bw0 + ((size_t)ex << 20);
    for (int kk = 0; kk < R1; kk += 64) {
      __syncthreads();  // LDS safe to overwrite
      if (kk == 0 && t < 128) wlds[t] = wsel[(size_t)(bm0 + t) * 64 + ex];
#pragma unroll
      for (int j = 0; j < 4; ++j) {
        GLDS16(au + (size_t)(j * 32) * R1 + kk, &Alds[(j * 32 + wv * 8) * 64]);
        GLDS16(bw + (size_t)(j * 32) * R1 + kk, &Blds[(j * 32 + wv * 8) * 64]);
      }
      __syncthreads();  // staging complete (vmcnt drained by barrier)

      const bf16_t* Ab = &Alds[(wm * 64 + l15) * 64];
      const bf16_t* Bb = &Blds[(wn * 64 + l15) * 64];
#pragma unroll
      for (int ks = 0; ks < 2; ++ks) {
        const int co = ((ks * 4 + quad) ^ fsw) * 8;  // swizzled chunk offset
        bf16x8 af[4], bfr[4];
#pragma unroll
        for (int i = 0; i < 4; ++i) {
          af[i]  = *(const bf16x8*)(Ab + i * 16 * 64 + co);
          bfr[i] = *(const bf16x8*)(Bb + i * 16 * 64 + co);
        }
#pragma unroll
        for (int mi = 0; mi < 4; ++mi)
#pragma unroll
          for (int ni = 0; ni < 4; ++ni)
            acc[mi][ni] = __builtin_amdgcn_mfma_f32_16x16x32_bf16(
                af[mi], bfr[ni], acc[mi][ni], 0, 0, 0);
      }
    }
    // per-expert epilogue: oacc += |acc| * w[b, ex]; reset acc
#pragma unroll
    for (int mi = 0; mi < 4; ++mi) {
      float wr[4];
#pragma unroll
      for (int r = 0; r < 4; ++r) wr[r] = wlds[wm * 64 + mi * 16 + quad * 4 + r];
#pragma unroll
      for (int ni = 0; ni < 4; ++ni)
#pragma unroll
        for (int r = 0; r < 4; ++r) {
          oacc[mi][ni][r] += fabsf(acc[mi][ni][r]) * wr[r];
          acc[mi][ni][r] = 0.f;
        }
    }
  }

  float* obase = is_y ? out : out + (size_t)BATCH * NOUT;
  const int oc = (is_y ? n0 : n0 - NOUT) + wn * 64 + l15;
#pragma unroll
  for (int mi = 0; mi < 4; ++mi)
#pragma unroll
    for (int ni = 0; ni < 4; ++ni)
#pragma unroll
      for (int r = 0; r < 4; ++r) {
        int brow = bm0 + wm * 64 + mi * 16 + quad * 4 + r;
        atomicAdd(&obase[(size_t)brow * NOUT + oc + ni * 16], oacc[mi][ni][r]);
      }
}

extern "C" void kernel_launch(void* const* d_in, const int* in_sizes, int n_in,
                              void* d_out, int out_size, void* d_ws, size_t ws_size,
                              hipStream_t stream) {
  const float* z    = (const float*)d_in[0];
  const float* u    = (const float*)d_in[1];
  const float* mem  = (const float*)d_in[2];
  const float* mu   = (const float*)d_in[3];
  const float* sig  = (const float*)d_in[4];
  const float* wcon = (const float*)d_in[5];
  const float* wrec = (const float*)d_in[6];
  float* out = (float*)d_out;

  char* ws = (char*)d_ws;
  bf16_t* ub  = (bf16_t*)ws;                              // 4 MiB
  bf16_t* wb  = (bf16_t*)(ws + ((size_t)4 << 20));        // 128 MiB
  float*  psw = (float*)(ws + ((size_t)132 << 20));       // 512 KiB
  float*  d2g = (float*)(ws + ((size_t)132 << 20) + ((size_t)512 << 10));

  hipMemsetAsync(d_out, 0, (size_t)out_size * sizeof(float), stream);
  cast_u_k<<<2048, 256, 0, stream>>>(u, ub);
  cast_w_k<<<8192, 256, 0, stream>>>(wcon, wrec, wb);
  psi_d2_k<<<dim3(64, 32), 256, 0, stream>>>(z, mu, sig, d2g);
  psi_sm_k<<<512, 256, 0, stream>>>(d2g, psw);
  fused_gemm<<<dim3(16, 8, 8), 256, 0, stream>>>(ub, wb, psw, mem, out);
}